// Round 10
// baseline (202.314 us; speedup 1.0000x reference)
//
#include <hip/hip_runtime.h>

// SSIM, 64 slices of 512x512, 11x11 uniform window (separable box), zero pad.
// R12: kill the o-row re-reads — 13-slot LDS ring keeps every streamed row
// alive for the 11 steps until it is subtracted. Evidence: seven structurally
// different kernels (R0,R4,R6,R7,R9,R11; TLP 4-16 waves/CU, DS-heavy/DS-free,
// compiler/hand-counted waits) ALL pin at ~7-8 B/cyc/CU of REQUESTED vmem
// traffic (R5 causally confirms: 2x bytes -> 2x time, same rate) => service-
// rate cap on the request stream (LLC path: o-row reuse gap 66k cyc >> L2
// lifetime ~16k cyc, so re-reads are LLC-served). Only lever left: fewer
// bytes. 344 MB -> 218 MB (-37%) by subtracting from the ring instead of
// re-loading. Ring: 13 slots x [cx 512][cy 512] floats = 52 KB, 3 blocks/CU.
// Prefetch depth 1, issue AFTER consume (slot s+2 overwrites row s-11's
// position, consumed that same step; sched_barrier pins the order).
// vmcnt ledger: prologue c0,c1 (8 outst.); step s: VW(4) -> c(s) landed
// [c(s+1) flying]; consume; issue c(s+2). Drain: VW(4)@24, VW(0)@25.
// Single-wave blocks, no barriers. DPP halo (R7), folded-K rational (R7),
// masked clamp loads (R9), o-mask fix (R11).

constexpr int IMG   = 512;
constexpr int RB    = 16;                 // output rows per wave (band)
constexpr int BANDS = IMG / RB;           // 32
constexpr int NBLK  = 64 * BANDS;         // 2048 single-wave blocks
constexpr int DSLOT = 13;                 // ring depth (11-window + depth-1)
constexpr float K1 = 1.4641f;             // 0.01^2 * 121^2
constexpr float K2 = 13.1769f;            // 0.03^2 * 121^2

// DPP whole-wave shifts. wave_shr:1 -> lane i reads lane i-1 (lane 0 zero);
// wave_shl:1 -> lane i reads lane i+1 (lane 63 zero). Zero-fill == image pad.
__device__ __forceinline__ float shr1(float v) {
  return __int_as_float(__builtin_amdgcn_update_dpp(
      0, __float_as_int(v), 0x138, 0xF, 0xF, true));
}
__device__ __forceinline__ float shl1(float v) {
  return __int_as_float(__builtin_amdgcn_update_dpp(
      0, __float_as_int(v), 0x130, 0xF, 0xF, true));
}

// async global->LDS, 16B per lane; LDS write = uniform base + lane*16.
__device__ __forceinline__ void gl16(const float* g, float* l) {
  __builtin_amdgcn_global_load_lds(
      (const __attribute__((address_space(1))) void*)g,
      (__attribute__((address_space(3))) void*)l, 16, 0, 0);
}

// hand-counted wait; "memory" clobber + sched_barrier keep LDS reads below it.
#define VW(n) do {                                                             \
    asm volatile("s_waitcnt vmcnt(%0)" :: "n"(n) : "memory");                  \
    __builtin_amdgcn_sched_barrier(0);                                         \
  } while (0)

template <bool ATOMIC>
__global__ __launch_bounds__(64, 1) void ssim_main(const float* __restrict__ x,
                                                   const float* __restrict__ y,
                                                   float* __restrict__ out_ws) {
  // ring slot (1024 floats = 4 KB): [cx 512][cy 512]; 13 slots = 52 KB.
  __shared__ float ring[DSLOT * 1024];

  const int lane = threadIdx.x;            // single wave per block
  // XCD clustering: 8 slices per XCD; adjacent bands (10-row halo overlap)
  // are adjacent blocks -> same XCD -> halo re-reads L2-hot.
  const int bid  = blockIdx.x;
  const int xcd  = bid & 7;
  const int qq   = bid >> 3;               // 0..255
  const int z    = xcd * 8 + (qq >> 5);    // slice 0..63
  const int band = qq & 31;                // 0..31
  const int o0   = band * RB;
  const int gs   = o0 - 5;                 // first streamed input row

  const float* xs = x + (size_t)z * IMG * IMG;
  const float* ys = y + (size_t)z * IMG * IMG;
  const int l4 = lane * 4;                 // float offset for 16B load granule
  const int lw = lane * 8;                 // float offset of this lane's 8 cols

  float sX[8] = {}, sY[8] = {}, sXX[8] = {}, sYY[8] = {}, sXY[8] = {};
  float acc = 0.f;

  auto issue_c = [&](int slot) {
    const int gr  = gs + slot;
    const int grc = gr < 0 ? 0 : (gr > IMG - 1 ? IMG - 1 : gr);
    const int pos = slot >= DSLOT ? slot - DSLOT : slot;   // slot % 13
    const int rb  = pos * 1024;
    const float* gx = xs + grc * IMG + l4;
    const float* gy = ys + grc * IMG + l4;
    gl16(gx,       &ring[rb]);
    gl16(gx + 256, &ring[rb + 256]);
    gl16(gy,       &ring[rb + 512]);
    gl16(gy + 256, &ring[rb + 768]);
  };

  // Horizontal 11-tap window sums for one quantity (DPP halo).
  auto hwin = [&](const float (&S)[8], float (&B)[8]) {
    const float vm5  = shr1(S[3]);
    const float vm4  = shr1(S[4]);
    const float vm3  = shr1(S[5]);
    const float vm2  = shr1(S[6]);
    const float vm1  = shr1(S[7]);
    const float vp8  = shl1(S[0]);
    const float vp9  = shl1(S[1]);
    const float vp10 = shl1(S[2]);
    const float vp11 = shl1(S[3]);
    const float vp12 = shl1(S[4]);
    float s = (((vm5 + vm4) + (vm3 + vm2)) + ((vm1 + S[0]) + (S[1] + S[2]))) +
              ((S[3] + S[4]) + S[5]);
    B[0] = s;
    s += S[6]  - vm5;  B[1] = s;
    s += S[7]  - vm4;  B[2] = s;
    s += vp8   - vm3;  B[3] = s;
    s += vp9   - vm2;  B[4] = s;
    s += vp10  - vm1;  B[5] = s;
    s += vp11  - S[0]; B[6] = s;
    s += vp12  - S[1]; B[7] = s;
  };

  auto outp = [&]() {
    float bX[8], bY[8], bXX[8], bYY[8], bXY[8];
    hwin(sX, bX); hwin(sY, bY); hwin(sXX, bXX); hwin(sYY, bYY); hwin(sXY, bXY);
    // SSIM with 1/121 folded: (N1*N2)/(D1*D2), 121^4 cancels.
#pragma unroll
    for (int j = 0; j < 8; ++j) {
      const float bx  = bX[j];
      const float by  = bY[j];
      const float bxy = bx * by;
      const float sq  = fmaf(bx, bx, by * by);
      const float n1  = fmaf(2.f, bxy, K1);
      const float n2  = fmaf(242.f, bXY[j], fmaf(-2.f, bxy, K2));
      const float d1  = sq + K1;
      const float d2  = fmaf(121.f, bXX[j] + bYY[j], K2 - sq);
      acc += (n1 * n2) * __builtin_amdgcn_rcpf(d1 * d2);
    }
  };

  // add new row (slot s) only — warmup and s=10
  auto consumeW = [&](int s) {
    const int pos = s >= DSLOT ? s - DSLOT : s;
    const int rb  = pos * 1024;
    const float mc = ((unsigned)(gs + s) < (unsigned)IMG) ? 1.f : 0.f;
    const float4 a = *(const float4*)&ring[rb + lw];
    const float4 b = *(const float4*)&ring[rb + lw + 4];
    const float4 c = *(const float4*)&ring[rb + 512 + lw];
    const float4 d = *(const float4*)&ring[rb + 512 + lw + 4];
    const float cx[8] = {a.x, a.y, a.z, a.w, b.x, b.y, b.z, b.w};
    const float cy[8] = {c.x, c.y, c.z, c.w, d.x, d.y, d.z, d.w};
#pragma unroll
    for (int j = 0; j < 8; ++j) {
      const float cxm = cx[j] * mc, cym = cy[j] * mc;
      sX[j] += cxm;
      sY[j] += cym;
      sXX[j] = fmaf(cx[j], cxm, sXX[j]);
      sYY[j] = fmaf(cy[j], cym, sYY[j]);
      sXY[j] = fmaf(cx[j], cym, sXY[j]);
    }
  };

  // add new row (slot s), subtract ring row (slot s-11), output
  auto consumeS = [&](int s) {
    const int pos = s >= DSLOT ? s - DSLOT : s;
    const int rb  = pos * 1024;
    const int so  = s - 11;                     // 0..14
    const int poso = so >= DSLOT ? so - DSLOT : so;
    const int ro  = poso * 1024;
    const float mc = ((unsigned)(gs + s) < (unsigned)IMG) ? 1.f : 0.f;
    const float mo = (gs + so >= 0) ? 1.f : 0.f;   // top-edge only (R11 fix)
    const float4 a = *(const float4*)&ring[rb + lw];
    const float4 b = *(const float4*)&ring[rb + lw + 4];
    const float4 c = *(const float4*)&ring[rb + 512 + lw];
    const float4 d = *(const float4*)&ring[rb + 512 + lw + 4];
    const float4 e = *(const float4*)&ring[ro + lw];
    const float4 f = *(const float4*)&ring[ro + lw + 4];
    const float4 g = *(const float4*)&ring[ro + 512 + lw];
    const float4 h = *(const float4*)&ring[ro + 512 + lw + 4];
    const float cx[8] = {a.x, a.y, a.z, a.w, b.x, b.y, b.z, b.w};
    const float cy[8] = {c.x, c.y, c.z, c.w, d.x, d.y, d.z, d.w};
    const float ox[8] = {e.x, e.y, e.z, e.w, f.x, f.y, f.z, f.w};
    const float oy[8] = {g.x, g.y, g.z, g.w, h.x, h.y, h.z, h.w};
#pragma unroll
    for (int j = 0; j < 8; ++j) {
      const float cxm = cx[j] * mc, cym = cy[j] * mc;
      const float oxm = ox[j] * mo, oym = oy[j] * mo;
      sX[j] += cxm - oxm;
      sY[j] += cym - oym;
      sXX[j] = fmaf(cx[j], cxm, fmaf(-ox[j], oxm, sXX[j]));
      sYY[j] = fmaf(cy[j], cym, fmaf(-oy[j], oym, sYY[j]));
      sXY[j] = fmaf(cx[j], cym, fmaf(-ox[j], oym, sXY[j]));
    }
    outp();
  };

  // ---- pipeline (26 streamed rows, 16 outputs) ----
  issue_c(0);
  issue_c(1);
#pragma unroll 1
  for (int s = 0; s < 10; ++s) {       // warmup rows gs..gs+9
    VW(4);
    consumeW(s);
    __builtin_amdgcn_sched_barrier(0);
    issue_c(s + 2);
  }
  // s = 10: first output row (sum rows 0..10, nothing leaves the window)
  VW(4);
  consumeW(10);
  outp();
  __builtin_amdgcn_sched_barrier(0);
  issue_c(12);
#pragma unroll 1
  for (int s = 11; s <= 23; ++s) {
    VW(4);
    consumeS(s);
    __builtin_amdgcn_sched_barrier(0);
    issue_c(s + 2);
  }
  VW(4);
  consumeS(24);
  VW(0);
  consumeS(25);

  // ---- reduction: single wave -> global ----
#pragma unroll
  for (int off = 32; off > 0; off >>= 1) acc += __shfl_down(acc, off, 64);
  if (lane == 0) {
    if (ATOMIC) {
      atomicAdd(out_ws, acc);
    } else {
      out_ws[bid] = acc;
    }
  }
}

__global__ void ssim_finalize(const float* __restrict__ partials, int n,
                              float* __restrict__ out) {
  __shared__ float wsum[4];
  float acc = 0.f;
  for (int i = threadIdx.x; i < n; i += 256) acc += partials[i];
#pragma unroll
  for (int off = 32; off > 0; off >>= 1) acc += __shfl_down(acc, off, 64);
  if ((threadIdx.x & 63) == 0) wsum[threadIdx.x >> 6] = acc;
  __syncthreads();
  if (threadIdx.x == 0) {
    const float t = wsum[0] + wsum[1] + wsum[2] + wsum[3];
    out[0] = 1.0f - t * (1.0f / (64.0f * 512.0f * 512.0f));
  }
}

__global__ void ssim_zero(float* p) {
  if (threadIdx.x == 0) p[0] = 0.f;
}

__global__ void ssim_finalize_atomic(const float* __restrict__ accp,
                                     float* __restrict__ out) {
  if (threadIdx.x == 0)
    out[0] = 1.0f - accp[0] * (1.0f / (64.0f * 512.0f * 512.0f));
}

extern "C" void kernel_launch(void* const* d_in, const int* in_sizes, int n_in,
                              void* d_out, int out_size, void* d_ws, size_t ws_size,
                              hipStream_t stream) {
  const float* x = (const float*)d_in[0];
  const float* y = (const float*)d_in[1];
  // d_in[2]: uniform 1/121 window, folded into K1/K2.
  float* out = (float*)d_out;

  dim3 grid(NBLK);      // 2048 single-wave blocks = 64 slices x 32 bands
  dim3 block(64);

  if (ws_size >= (size_t)NBLK * sizeof(float)) {
    float* partials = (float*)d_ws;
    ssim_main<false><<<grid, block, 0, stream>>>(x, y, partials);
    ssim_finalize<<<1, 256, 0, stream>>>(partials, NBLK, out);
  } else {
    float* accp = (float*)d_ws;
    ssim_zero<<<1, 64, 0, stream>>>(accp);
    ssim_main<true><<<grid, block, 0, stream>>>(x, y, accp);
    ssim_finalize_atomic<<<1, 64, 0, stream>>>(accp, out);
  }
}

// Round 11
// 191.424 us; speedup vs baseline: 1.0569x; 1.0569x over previous
//
#include <hip/hip_runtime.h>

// SSIM, 64 slices of 512x512, 11x11 uniform window (separable box), zero pad.
// R13: block-shared LDS ring — few bytes AND high concurrency simultaneously.
// Evidence: all designs with >=6 waves/CU pin at 4.1-4.8 TB/s request rate
// (R9: 344 MB -> 72us); R12 cut bytes 37% but starved concurrency (3 waves/CU,
// 2.3 TB/s) -> slower. Model: ~4.5 TB/s saturable service cap; minimize bytes
// while keeping enough outstanding loads to saturate it.
// Design: 256-thread block = 4 full-row waves = 4 consecutive bands of one
// slice (64 output rows). Block streams 74 rows ONCE through a shared
// 16-slot x 4KB LDS ring (64KB -> 2 blocks/CU = 8 waves/CU). Loader duty
// round-robins: at step s, wave (s&3) issued row s 4 steps earlier (deep
// slack), waits vmcnt(0) on ITS OWN queue, then RAW s_barrier publishes the
// row (NOT __syncthreads: that emits vmcnt(0) for all waves and drains their
// prefetches — the GEMM barrier-drain trap). Ring safety: step-s issue writes
// slot of row s-12 (last read step s-1, protected by barrier s); concurrent
// readers touch rows s and s-11 only. Requests: 512 x 74 x 4KB = 155 MB
// (1.16x ideal). DPP halo (R7), folded-K rational (R7), masked clamp loads
// (R9/R11 o-mask fix).

constexpr int IMG   = 512;
constexpr int GRB   = 64;                 // output rows per block (4 bands)
constexpr int NROW  = GRB + 10;           // 74 streamed rows per block
constexpr int NBLK  = 64 * (IMG / GRB);   // 512 blocks
constexpr int SLOTS = 16;                 // ring depth (11 window + 4 flight +1)
constexpr float K1 = 1.4641f;             // 0.01^2 * 121^2
constexpr float K2 = 13.1769f;            // 0.03^2 * 121^2

// DPP whole-wave shifts. wave_shr:1 -> lane i reads lane i-1 (lane 0 zero);
// wave_shl:1 -> lane i reads lane i+1 (lane 63 zero). Zero-fill == image pad.
__device__ __forceinline__ float shr1(float v) {
  return __int_as_float(__builtin_amdgcn_update_dpp(
      0, __float_as_int(v), 0x138, 0xF, 0xF, true));
}
__device__ __forceinline__ float shl1(float v) {
  return __int_as_float(__builtin_amdgcn_update_dpp(
      0, __float_as_int(v), 0x130, 0xF, 0xF, true));
}

// async global->LDS, 16B per lane; LDS dest = wave-uniform base + lane*16.
__device__ __forceinline__ void gl16(const float* g, float* l) {
  __builtin_amdgcn_global_load_lds(
      (const __attribute__((address_space(1))) void*)g,
      (__attribute__((address_space(3))) void*)l, 16, 0, 0);
}

template <bool ATOMIC>
__global__ __launch_bounds__(256, 2) void ssim_main(const float* __restrict__ x,
                                                    const float* __restrict__ y,
                                                    float* __restrict__ out_ws) {
  // ring slot (1024 floats = 4KB): [x-row 512][y-row 512]; 16 slots = 64KB.
  __shared__ float ring[SLOTS * 1024];
  __shared__ float wsum[4];

  const int tid  = threadIdx.x;
  const int lane = tid & 63;
  const int wid  = tid >> 6;

  // XCD clustering: 8 slices per XCD; consecutive blocks = consecutive
  // 64-row groups of one slice (10-row halo overlap stays L2-hot).
  const int bid  = blockIdx.x;
  const int xcd  = bid & 7;
  const int qq   = bid >> 3;               // 0..63
  const int z    = xcd * 8 + (qq >> 3);    // slice 0..63
  const int g    = qq & 7;                 // 64-row group 0..7
  const int R0   = g * GRB - 5;            // first streamed image row

  const float* xs = x + (size_t)z * IMG * IMG;
  const float* ys = y + (size_t)z * IMG * IMG;
  const int l4 = lane * 4;                 // 16B-granule float offset
  const int lw = lane * 8;                 // this lane's 8-col float offset

  float sX[8] = {}, sY[8] = {}, sXX[8] = {}, sYY[8] = {}, sXY[8] = {};
  float acc = 0.f;

  // issue row-step s (all 64 lanes of the calling wave participate)
  auto issue_row = [&](int s) {
    const int r   = R0 + s;
    const int rc  = r < 0 ? 0 : (r > IMG - 1 ? IMG - 1 : r);
    float* sb = &ring[(s & (SLOTS - 1)) * 1024];
    const float* gx = xs + rc * IMG + l4;
    const float* gy = ys + rc * IMG + l4;
    gl16(gx,       sb);
    gl16(gx + 256, sb + 256);
    gl16(gy,       sb + 512);
    gl16(gy + 256, sb + 768);
  };

  // Horizontal 11-tap window sums for one quantity (DPP halo).
  auto hwin = [&](const float (&S)[8], float (&B)[8]) {
    const float vm5  = shr1(S[3]);
    const float vm4  = shr1(S[4]);
    const float vm3  = shr1(S[5]);
    const float vm2  = shr1(S[6]);
    const float vm1  = shr1(S[7]);
    const float vp8  = shl1(S[0]);
    const float vp9  = shl1(S[1]);
    const float vp10 = shl1(S[2]);
    const float vp11 = shl1(S[3]);
    const float vp12 = shl1(S[4]);
    float s = (((vm5 + vm4) + (vm3 + vm2)) + ((vm1 + S[0]) + (S[1] + S[2]))) +
              ((S[3] + S[4]) + S[5]);
    B[0] = s;
    s += S[6]  - vm5;  B[1] = s;
    s += S[7]  - vm4;  B[2] = s;
    s += vp8   - vm3;  B[3] = s;
    s += vp9   - vm2;  B[4] = s;
    s += vp10  - vm1;  B[5] = s;
    s += vp11  - S[0]; B[6] = s;
    s += vp12  - S[1]; B[7] = s;
  };

  auto outp = [&]() {
    float bX[8], bY[8], bXX[8], bYY[8], bXY[8];
    hwin(sX, bX); hwin(sY, bY); hwin(sXX, bXX); hwin(sYY, bYY); hwin(sXY, bXY);
    // SSIM with 1/121 folded: (N1*N2)/(D1*D2), 121^4 cancels.
#pragma unroll
    for (int j = 0; j < 8; ++j) {
      const float bx  = bX[j];
      const float by  = bY[j];
      const float bxy = bx * by;
      const float sq  = fmaf(bx, bx, by * by);
      const float n1  = fmaf(2.f, bxy, K1);
      const float n2  = fmaf(242.f, bXY[j], fmaf(-2.f, bxy, K2));
      const float d1  = sq + K1;
      const float d2  = fmaf(121.f, bXX[j] + bYY[j], K2 - sq);
      acc += (n1 * n2) * __builtin_amdgcn_rcpf(d1 * d2);
    }
  };

  // ---- prologue: wave w issues row w ----
  issue_row(wid);

#pragma unroll 1
  for (int s = 0; s < NROW; ++s) {
    // Loader wave: its row-s loads (issued 4 steps ago) must land before the
    // barrier publishes them. vmcnt is wave-local: only its own 4 loads.
    if (wid == (s & 3)) {
      asm volatile("s_waitcnt vmcnt(0)" ::: "memory");
      __builtin_amdgcn_sched_barrier(0);
    }
    __builtin_amdgcn_s_barrier();       // raw: no vmcnt drain of other waves
    __builtin_amdgcn_sched_barrier(0);

    const int t = s - 16 * wid;         // wave-local step in its 26-step window
    if (t >= 0 && t <= 25) {
      const int r  = R0 + s;
      const float mc = ((unsigned)r < (unsigned)IMG) ? 1.f : 0.f;
      const float* sb = &ring[(s & (SLOTS - 1)) * 1024];
      const float4 a = *(const float4*)(sb + lw);
      const float4 b = *(const float4*)(sb + lw + 4);
      const float4 c = *(const float4*)(sb + 512 + lw);
      const float4 d = *(const float4*)(sb + 512 + lw + 4);
      const float cx[8] = {a.x, a.y, a.z, a.w, b.x, b.y, b.z, b.w};
      const float cy[8] = {c.x, c.y, c.z, c.w, d.x, d.y, d.z, d.w};
      if (t < 11) {                     // pure accumulate (t=10 also outputs)
#pragma unroll
        for (int j = 0; j < 8; ++j) {
          const float cxm = cx[j] * mc, cym = cy[j] * mc;
          sX[j] += cxm;
          sY[j] += cym;
          sXX[j] = fmaf(cx[j], cxm, sXX[j]);
          sYY[j] = fmaf(cy[j], cym, sYY[j]);
          sXY[j] = fmaf(cx[j], cym, sXY[j]);
        }
        if (t == 10) outp();
      } else {                          // add row s, subtract row s-11
        const float mo = ((unsigned)(r - 11) < (unsigned)IMG) ? 1.f : 0.f;
        const float* so = &ring[((s - 11) & (SLOTS - 1)) * 1024];
        const float4 e = *(const float4*)(so + lw);
        const float4 f = *(const float4*)(so + lw + 4);
        const float4 gg = *(const float4*)(so + 512 + lw);
        const float4 h = *(const float4*)(so + 512 + lw + 4);
        const float ox[8] = {e.x, e.y, e.z, e.w, f.x, f.y, f.z, f.w};
        const float oy[8] = {gg.x, gg.y, gg.z, gg.w, h.x, h.y, h.z, h.w};
#pragma unroll
        for (int j = 0; j < 8; ++j) {
          const float cxm = cx[j] * mc, cym = cy[j] * mc;
          const float oxm = ox[j] * mo, oym = oy[j] * mo;
          sX[j] += cxm - oxm;
          sY[j] += cym - oym;
          sXX[j] = fmaf(cx[j], cxm, fmaf(-ox[j], oxm, sXX[j]));
          sYY[j] = fmaf(cy[j], cym, fmaf(-oy[j], oym, sYY[j]));
          sXY[j] = fmaf(cx[j], cym, fmaf(-ox[j], oym, sXY[j]));
        }
        outp();
      }
    }
    __builtin_amdgcn_sched_barrier(0);
    // Loader issues row s+4 into slot of row s-12 (dead: last read step s-1,
    // all waves past barrier s). Writes land any time before its next VW(0).
    if (wid == (s & 3) && s + 4 < NROW) issue_row(s + 4);
  }

  // ---- reduction: wave -> block -> global (loads all drained by VW(0)s) ----
#pragma unroll
  for (int off = 32; off > 0; off >>= 1) acc += __shfl_down(acc, off, 64);
  if (lane == 0) wsum[wid] = acc;
  __syncthreads();
  if (tid == 0) {
    const float t = wsum[0] + wsum[1] + wsum[2] + wsum[3];
    if (ATOMIC) {
      atomicAdd(out_ws, t);
    } else {
      out_ws[bid] = t;
    }
  }
}

__global__ void ssim_finalize(const float* __restrict__ partials, int n,
                              float* __restrict__ out) {
  __shared__ float wsum[4];
  float acc = 0.f;
  for (int i = threadIdx.x; i < n; i += 256) acc += partials[i];
#pragma unroll
  for (int off = 32; off > 0; off >>= 1) acc += __shfl_down(acc, off, 64);
  if ((threadIdx.x & 63) == 0) wsum[threadIdx.x >> 6] = acc;
  __syncthreads();
  if (threadIdx.x == 0) {
    const float t = wsum[0] + wsum[1] + wsum[2] + wsum[3];
    out[0] = 1.0f - t * (1.0f / (64.0f * 512.0f * 512.0f));
  }
}

__global__ void ssim_zero(float* p) {
  if (threadIdx.x == 0) p[0] = 0.f;
}

__global__ void ssim_finalize_atomic(const float* __restrict__ accp,
                                     float* __restrict__ out) {
  if (threadIdx.x == 0)
    out[0] = 1.0f - accp[0] * (1.0f / (64.0f * 512.0f * 512.0f));
}

extern "C" void kernel_launch(void* const* d_in, const int* in_sizes, int n_in,
                              void* d_out, int out_size, void* d_ws, size_t ws_size,
                              hipStream_t stream) {
  const float* x = (const float*)d_in[0];
  const float* y = (const float*)d_in[1];
  // d_in[2]: uniform 1/121 window, folded into K1/K2.
  float* out = (float*)d_out;

  dim3 grid(NBLK);      // 512 blocks x 256 threads; 2 blocks/CU (64KB LDS)
  dim3 block(256);

  if (ws_size >= (size_t)NBLK * sizeof(float)) {
    float* partials = (float*)d_ws;
    ssim_main<false><<<grid, block, 0, stream>>>(x, y, partials);
    ssim_finalize<<<1, 256, 0, stream>>>(partials, NBLK, out);
  } else {
    float* accp = (float*)d_ws;
    ssim_zero<<<1, 64, 0, stream>>>(accp);
    ssim_main<true><<<grid, block, 0, stream>>>(x, y, accp);
    ssim_finalize_atomic<<<1, 64, 0, stream>>>(accp, out);
  }
}